// Round 18
// baseline (335.794 us; speedup 1.0000x reference)
//
#include <hip/hip_runtime.h>
#include <stdint.h>

typedef int v4i  __attribute__((ext_vector_type(4)));
typedef int v16i __attribute__((ext_vector_type(16)));

#define CAPACITY  65536
#define BATCH     2048
#define KBITS     1024
#define NSTEP     8       // K-steps of 128 bytes (BK=128)

// ===========================================================================
// MFMA path: dist(q,k) = sumq + sumk - 2*dot(q,k). sumq constant per query
// row -> dropped; rank by packed ((sumk - 2*dot + 2048)<<16) | key_idx, exact
// (0 <= biased dist <= 3072 < 2^16), reproduces first-max argmax.
//
// r18 = r14 geometry (256M x 64N block, 4 waves = 4 M-rows, wave 64x64,
// mtile-inner XCD-pinned) with BK doubled to 128: 16 MFMA per barrier, half
// the sync points (every structure with sync-per-K=64 plateaued at 4200
// cyc/step vs 1171 cyc MFMA demand; r17 falsified phase-locking, so the
// remaining sync-side lever is sync FREQUENCY, per m233/m97).
// Wait ledger (per-wave, in-order queue):
//   bottom of s: issue af01(s+1)[4] + stage(s+2)[2]; barrier with 6 in flight
//   (a) top of s (after issuing af23(s)[4]): vmcnt(6) -> retires af01(s)
//   (c) mid of s: vmcnt(0) -> retires stage(s+1) (full step old) + af23(s)
//       (covered by km0+km1 clusters); also the LDS-visibility handshake:
//       every wave drains its stage(s+1)/(s+2) shares here, >=1 barrier
//       before those buffers are read.
// ===========================================================================

// ---- queries: bits -> i8, K-plane-major qT[kplane(64)][row][16B] ------------
__global__ void prep_qT_kernel(const int* __restrict__ in,
                               uint32_t* __restrict__ outT) {
    const int row = blockIdx.x, t = threadIdx.x;   // t covers bits 4t..4t+3
    int4 v = reinterpret_cast<const int4*>(in)[(size_t)row * 256 + t];
    uint32_t b = (uint32_t)(v.x & 1)        | ((uint32_t)(v.y & 1) << 8) |
                 ((uint32_t)(v.z & 1) << 16) | ((uint32_t)(v.w & 1) << 24);
    outT[(size_t)(t >> 2) * (BATCH * 4) + (size_t)row * 4 + (t & 3)] = b;
}

// ---- keys: bits -> i8 row-major, plus per-row bit count ---------------------
__global__ void prep_i8_kernel(const int* __restrict__ in,
                               unsigned char* __restrict__ out8,
                               int* __restrict__ sums) {
    const int row = blockIdx.x, t = threadIdx.x;
    int4 v = reinterpret_cast<const int4*>(in)[(size_t)row * 256 + t];
    uint32_t b = (uint32_t)(v.x & 1)        | ((uint32_t)(v.y & 1) << 8) |
                 ((uint32_t)(v.z & 1) << 16) | ((uint32_t)(v.w & 1) << 24);
    reinterpret_cast<uint32_t*>(out8)[(size_t)row * 256 + t] = b;
    int s = (v.x & 1) + (v.y & 1) + (v.z & 1) + (v.w & 1);
    for (int off = 32; off; off >>= 1) s += __shfl_xor(s, off, 64);
    __shared__ int ws4[4];
    if ((t & 63) == 0) ws4[t >> 6] = s;
    __syncthreads();
    if (t == 0) sums[row] = ws4[0] + ws4[1] + ws4[2] + ws4[3];
}

__global__ void init_best_kernel(uint32_t* __restrict__ best) {
    best[blockIdx.x * 256 + threadIdx.x] = 0xFFFFFFFFu;
}

// Involutive 16B-chunk swizzle for a [64 rows][128B] tile (idx = row*8+chunk).
// chunk ^= (row ^ row>>3) & 7: lanes {ln, ln+8, ln+16, ln+24} (which share
// ln&7 at the 128B stride) get distinct chunks -> distinct bank quads.
// Bits >=3 untouched -> self-inverse, so staging sources can be pre-swizzled
// with the SAME function while LDS stays linear (rule #21 pattern).
__device__ __forceinline__ int swz2(int idx) {
    return idx ^ (((idx >> 3) ^ (idx >> 6)) & 7);
}

// ---- GEMM + fused argmin ---------------------------------------------------
__launch_bounds__(256, 4)
__global__ void gemm_scan_kernel(const uint4* __restrict__ aT4,
                                 const unsigned char* __restrict__ ki8,
                                 const int* __restrict__ sumk,
                                 uint32_t* __restrict__ best) {
    __shared__ uint4 sB[3][512];   // 3 x (64 rows x 8 chunks x 16B) = 24 KB

    const int t    = threadIdx.x;
    const int lane = t & 63, wid = t >> 6;        // wid = wave M-row
    const int ln   = lane & 31, kh = lane >> 5;   // mfma lane, k-half

    // mtile-inner, XCD-pinned: xcd = b&7 owns 128 ntiles; 8 consecutive
    // blocks share one B-tile (L2-hot); A (2 MB qT) cycles through L2.
    const int b     = blockIdx.x;
    const int slot  = b >> 3;                      // [0,1024)
    const int ntile = (b & 7) * 128 + (slot >> 3); // [0,1024)
    const int mtile = slot & 7;                    // [0,8)
    const int m0 = mtile * 256, n0 = ntile * 64;

    // B staging: 512 16B-chunks, 256 threads x 2; sources pre-swizzled.
    const int s0 = swz2(t), s1 = swz2(256 + t);
    const unsigned char* bSrc0 = ki8 + (size_t)(n0 + (s0 >> 3)) * KBITS + (s0 & 7) * 16;
    const unsigned char* bSrc1 = ki8 + (size_t)(n0 + (s1 >> 3)) * KBITS + (s1 & 7) * 16;
    auto STAGE_B = [&](int buf, int kc) {          // 2 x global_load_lds(16B)
        __builtin_amdgcn_global_load_lds(
            (const __attribute__((address_space(1))) void*)(bSrc0 + kc),
            (__attribute__((address_space(3))) void*)&sB[buf][t], 16, 0, 0);
        __builtin_amdgcn_global_load_lds(
            (const __attribute__((address_space(1))) void*)(bSrc1 + kc),
            (__attribute__((address_space(3))) void*)&sB[buf][256 + t], 16, 0, 0);
    };

    // B fragment LDS offsets (K-invariant): [km(4)][ct(2)]
    int offB[4][2];
#pragma unroll
    for (int km = 0; km < 4; ++km)
#pragma unroll
        for (int ct = 0; ct < 2; ++ct)
            offB[km][ct] = swz2((ct * 32 + ln) * 8 + km * 2 + kh);

    const int mbase = m0 + wid * 64 + ln;          // unique per wave

    v16i acc[2][2];
#pragma unroll
    for (int rt = 0; rt < 2; ++rt)
#pragma unroll
        for (int ct = 0; ct < 2; ++ct)
#pragma unroll
            for (int e = 0; e < 16; ++e) acc[rt][ct][e] = 0;

    uint4 af01[2][2], af23[2][2];                  // [km-half][rt]
    auto LOAD_AF01 = [&](int s) {                  // kplanes s*8 + {0..3}
#pragma unroll
        for (int km = 0; km < 2; ++km)
#pragma unroll
            for (int rt = 0; rt < 2; ++rt)
                af01[km][rt] = aT4[(size_t)(s * 8 + km * 2 + kh) * BATCH
                                   + mbase + rt * 32];
    };
    auto LOAD_AF23 = [&](int s) {                  // kplanes s*8 + {4..7}
#pragma unroll
        for (int km = 0; km < 2; ++km)
#pragma unroll
            for (int rt = 0; rt < 2; ++rt)
                af23[km][rt] = aT4[(size_t)(s * 8 + 4 + km * 2 + kh) * BATCH
                                   + mbase + rt * 32];
    };

    // prologue: queue = [stage(0)2, af01(0)4, stage(1)2]
    STAGE_B(0, 0);
    LOAD_AF01(0);
    STAGE_B(1, 128);
    asm volatile("s_waitcnt vmcnt(6)" ::: "memory");  // retire stage(0)
    __builtin_amdgcn_s_barrier();

#pragma unroll
    for (int s = 0; s < NSTEP; ++s) {
        const int buf = s % 3;

        LOAD_AF23(s);                              // 4 loads (newest)

        uint4 bf[2][2];
#pragma unroll
        for (int ct = 0; ct < 2; ++ct) bf[0][ct] = sB[buf][offB[0][ct]];
#pragma unroll
        for (int ct = 0; ct < 2; ++ct) bf[1][ct] = sB[buf][offB[1][ct]];

        // (a) retire af01(s) [oldest 4]; keep stage(s+1)2 + af23(s)4
        if (s < NSTEP - 1)
            asm volatile("s_waitcnt vmcnt(6) lgkmcnt(2)" ::: "memory");
        else
            asm volatile("s_waitcnt vmcnt(4) lgkmcnt(2)" ::: "memory");
        __builtin_amdgcn_sched_barrier(0);

        __builtin_amdgcn_s_setprio(1);
#pragma unroll
        for (int rt = 0; rt < 2; ++rt)             // km0
#pragma unroll
            for (int ct = 0; ct < 2; ++ct)
                acc[rt][ct] = __builtin_amdgcn_mfma_i32_32x32x32_i8(
                    *(v4i*)&af01[0][rt], *(v4i*)&bf[0][ct], acc[rt][ct], 0, 0, 0);
        __builtin_amdgcn_s_setprio(0);

        asm volatile("s_waitcnt lgkmcnt(0)" ::: "memory");
        __builtin_amdgcn_sched_barrier(0);

        __builtin_amdgcn_s_setprio(1);
#pragma unroll
        for (int rt = 0; rt < 2; ++rt)             // km1
#pragma unroll
            for (int ct = 0; ct < 2; ++ct)
                acc[rt][ct] = __builtin_amdgcn_mfma_i32_32x32x32_i8(
                    *(v4i*)&af01[1][rt], *(v4i*)&bf[1][ct], acc[rt][ct], 0, 0, 0);
        __builtin_amdgcn_s_setprio(0);

#pragma unroll
        for (int ct = 0; ct < 2; ++ct) bf[0][ct] = sB[buf][offB[2][ct]];
#pragma unroll
        for (int ct = 0; ct < 2; ++ct) bf[1][ct] = sB[buf][offB[3][ct]];

        // (c) retire stage(s+1) (full step old) + af23(s) (covered by km0/km1)
        asm volatile("s_waitcnt vmcnt(0) lgkmcnt(2)" ::: "memory");
        __builtin_amdgcn_sched_barrier(0);

        __builtin_amdgcn_s_setprio(1);
#pragma unroll
        for (int rt = 0; rt < 2; ++rt)             // km2
#pragma unroll
            for (int ct = 0; ct < 2; ++ct)
                acc[rt][ct] = __builtin_amdgcn_mfma_i32_32x32x32_i8(
                    *(v4i*)&af23[0][rt], *(v4i*)&bf[0][ct], acc[rt][ct], 0, 0, 0);
        __builtin_amdgcn_s_setprio(0);

        asm volatile("s_waitcnt lgkmcnt(0)" ::: "memory");
        __builtin_amdgcn_sched_barrier(0);

        __builtin_amdgcn_s_setprio(1);
#pragma unroll
        for (int rt = 0; rt < 2; ++rt)             // km3
#pragma unroll
            for (int ct = 0; ct < 2; ++ct)
                acc[rt][ct] = __builtin_amdgcn_mfma_i32_32x32x32_i8(
                    *(v4i*)&af23[1][rt], *(v4i*)&bf[1][ct], acc[rt][ct], 0, 0, 0);
        __builtin_amdgcn_s_setprio(0);

        // bottom: issue next step's af01 + stage; cross barrier with 6 in
        // flight (no waitcnt before the barrier — lgkm already drained).
        if (s + 1 < NSTEP) LOAD_AF01(s + 1);
        if (s + 2 < NSTEP) STAGE_B((s + 2) % 3, (s + 2) * 128);
        if (s < NSTEP - 1) __builtin_amdgcn_s_barrier();
    }

    // ---- epilogue: packed argmin, exact tie-break (verified r6-r17) -------
    int sk[2];
#pragma unroll
    for (int ct = 0; ct < 2; ++ct) sk[ct] = sumk[n0 + ct * 32 + ln];

#pragma unroll
    for (int rt = 0; rt < 2; ++rt) {
#pragma unroll
        for (int r = 0; r < 16; ++r) {
            // verified C/D map: col = lane&31, row = (r&3)+8*(r>>2)+4*(lane>>5)
            const int qrow = m0 + wid * 64 + rt * 32 + (r & 3) + 8 * (r >> 2) + 4 * kh;
            uint32_t bmin = 0xFFFFFFFFu;
#pragma unroll
            for (int ct = 0; ct < 2; ++ct) {
                uint32_t dist = (uint32_t)(sk[ct] - 2 * acc[rt][ct][r] + 2048);
                uint32_t col  = (uint32_t)(n0 + ct * 32 + ln);
                bmin = min(bmin, (dist << 16) | col);
            }
#pragma unroll
            for (int off = 1; off < 32; off <<= 1)   // reduce within 32 cols
                bmin = min(bmin, (uint32_t)__shfl_xor((int)bmin, off, 64));
            if (ln == 0) atomicMin(&best[qrow], bmin);
        }
    }
}

// ---- best[q] -> gather values row ------------------------------------------
__global__ void finalize_kernel(const uint32_t* __restrict__ best,
                                const float* __restrict__ values,
                                float* __restrict__ out) {
    const int qy  = blockIdx.x;
    const int idx = (int)(best[qy] & 0xFFFFu);
    const float4* v4 = reinterpret_cast<const float4*>(values) + (size_t)idx * 256;
    float4* o4 = reinterpret_cast<float4*>(out) + (size_t)qy * 256;
    o4[threadIdx.x] = v4[threadIdx.x];
}

// ===========================================================================
// Fallback (round-5 VALU scan, 401 us) if ws_size can't hold i8 keys
// ===========================================================================
#define KCHUNK 256
#define NSPLIT (CAPACITY / KCHUNK)

__device__ __forceinline__ uint32_t pack_word(const int4* __restrict__ p) {
    uint32_t word = 0;
#pragma unroll
    for (int j = 0; j < 8; ++j) {
        int4 v = p[j];
        word |= (uint32_t)(v.x & 1) << (4 * j + 0);
        word |= (uint32_t)(v.y & 1) << (4 * j + 1);
        word |= (uint32_t)(v.z & 1) << (4 * j + 2);
        word |= (uint32_t)(v.w & 1) << (4 * j + 3);
    }
    return word;
}

__global__ void pack_bits_kernel(const int* __restrict__ in,
                                 uint32_t* __restrict__ out, int nwords) {
    int w = blockIdx.x * blockDim.x + threadIdx.x;
    if (w >= nwords) return;
    out[w] = pack_word(reinterpret_cast<const int4*>(in) + (size_t)w * 8);
}

__launch_bounds__(256, 4)
__global__ void scan_kernel(const uint32_t* __restrict__ qpack,
                            const uint32_t* __restrict__ kpack,
                            uint32_t* __restrict__ best) {
    const int t      = threadIdx.x;
    const int lane   = t & 63;
    const int wid    = t >> 6;
    const int ksplit = blockIdx.x & (NSPLIT - 1);
    const int qgb    = blockIdx.x >> 8;
    const int query  = qgb * 256 + wid * 64 + lane;

    uint32_t q[32];
    const uint4* qp4 = reinterpret_cast<const uint4*>(qpack + (size_t)query * 32);
#pragma unroll
    for (int j = 0; j < 8; ++j) {
        uint4 v = qp4[j];
        q[4 * j + 0] = v.x; q[4 * j + 1] = v.y;
        q[4 * j + 2] = v.z; q[4 * j + 3] = v.w;
    }
    uint32_t bst = 0xFFFFFFFFu;
    const int k0 = ksplit * KCHUNK;
#pragma unroll 2
    for (int k = k0; k < k0 + KCHUNK; ++k) {
        const uint4* kw4 = reinterpret_cast<const uint4*>(kpack + (size_t)k * 32);
        uint32_t dist = 0;
#pragma unroll
        for (int j = 0; j < 8; ++j) {
            uint4 kv = kw4[j];
            dist += __popc(kv.x ^ q[4 * j + 0]);
            dist += __popc(kv.y ^ q[4 * j + 1]);
            dist += __popc(kv.z ^ q[4 * j + 2]);
            dist += __popc(kv.w ^ q[4 * j + 3]);
        }
        bst = min(bst, (dist << 16) | (uint32_t)k);
    }
    atomicMin(&best[query], bst);
}

// ===========================================================================
extern "C" void kernel_launch(void* const* d_in, const int* in_sizes, int n_in,
                              void* d_out, int out_size, void* d_ws, size_t ws_size,
                              hipStream_t stream) {
    const int*   query  = (const int*)d_in[0];   // [2048, 1024] int32 0/1
    const int*   keys   = (const int*)d_in[1];   // [65536, 1024] int32 0/1
    const float* values = (const float*)d_in[2]; // [65536, 1024] f32
    float*       out    = (float*)d_out;         // [2048, 1024] f32
    char* ws = (char*)d_ws;

    const size_t need = 2097152ULL + 67108864ULL + 262144ULL + 8192ULL;
    if (ws_size >= need) {
        uint32_t* qT  = (uint32_t*)ws;                           // 2 MB K-plane-major
        unsigned char* ki8 = (unsigned char*)(ws + 2097152);     // 64 MB
        int* sumk = (int*)(ws + 2097152 + 67108864);             // 256 KB
        uint32_t* best = (uint32_t*)(ws + 2097152 + 67108864 + 262144);

        init_best_kernel<<<BATCH / 256, 256, 0, stream>>>(best);
        prep_qT_kernel<<<BATCH,    256, 0, stream>>>(query, qT);
        prep_i8_kernel<<<CAPACITY, 256, 0, stream>>>(keys, ki8, sumk);
        gemm_scan_kernel<<<8192, 256, 0, stream>>>(
            reinterpret_cast<const uint4*>(qT), ki8, sumk, best);
        finalize_kernel<<<BATCH, 256, 0, stream>>>(best, values, out);
    } else {
        uint32_t* qpack = (uint32_t*)ws;                         // 256 KB
        uint32_t* kpack = (uint32_t*)(ws + 262144);              // 8 MB
        uint32_t* best  = (uint32_t*)(ws + 262144 + 8388608);    // 8 KB

        init_best_kernel<<<BATCH / 256, 256, 0, stream>>>(best);
        pack_bits_kernel<<<BATCH * 32 / 256, 256, 0, stream>>>(query, qpack, BATCH * 32);
        pack_bits_kernel<<<CAPACITY * 32 / 256, 256, 0, stream>>>(keys, kpack, CAPACITY * 32);
        scan_kernel<<<8 * NSPLIT, 256, 0, stream>>>(qpack, kpack, best);
        finalize_kernel<<<BATCH, 256, 0, stream>>>(best, values, out);
    }
}